// Round 5
// baseline (170.619 us; speedup 1.0000x reference)
//
#include <hip/hip_runtime.h>
#include <math.h>

#define GRIDN 128
#define NSAMP 192
#define BLOCK 256
#define REPS  8   // diagnostic: make dispatch long enough to reach rocprof top-5

__global__ __launch_bounds__(BLOCK) void plenoxel_render_kernel(
    const float* __restrict__ vox_grid,   // [128][128][128][28]
    const float* __restrict__ origins,    // [R][3]
    const float* __restrict__ dirs_in,    // [R][3]
    const float* __restrict__ zero_p,     // d_ws, first float == 0.0f
    float* __restrict__ out)              // [R][3]
{
    __shared__ uint2  ow_s[NSAMP][8];      // {byte offset, weight bits} per corner
    __shared__ float4 vox_s[NSAMP * 7];    // reduced 28 floats per sample
    __shared__ float  wtot[3];
    __shared__ float  redr[3], redg[3], redb[3];

    const int ray  = blockIdx.x;
    const int tid  = threadIdx.x;
    const int lane = tid & 63;
    const int wave = tid >> 6;              // 0..3

    // ---- per-ray setup (uniform per block) ----
    const float ox = origins[ray * 3 + 0];
    const float oy = origins[ray * 3 + 1];
    const float oz = origins[ray * 3 + 2];
    float dx = dirs_in[ray * 3 + 0];
    float dy = dirs_in[ray * 3 + 1];
    float dz = dirs_in[ray * 3 + 2];
    const float rn = 1.0f / sqrtf(dx * dx + dy * dy + dz * dz);
    dx *= rn; dy *= rn; dz *= rn;

    const float zero = zero_p[0];           // 0.0f, opaque to compiler (anti-LICM)

    for (int rep = 0; rep < REPS; ++rep) {

    // ---- phase 0: per-sample corner offsets + weights (thread = sample) ----
    if (tid < NSAMP) {
        const float t  = (float)tid + zero * (float)rep;   // == tid, rep-dependent
        const float px = fmaf(dx, t, ox);
        const float py = fmaf(dy, t, oy);
        const float pz = fmaf(dz, t, oz);
        const float fx = floorf(px), fy = floorf(py), fz = floorf(pz);
        const int   ix = (int)fx, iy = (int)fy, iz = (int)fz;
        const float rx = px - fx, ry = py - fy, rz = pz - fz;
        #pragma unroll
        for (int g = 0; g < 8; ++g) {
            const int cx = (g >> 2) & 1, cy = (g >> 1) & 1, cz = g & 1;
            const int X = ix + cx, Y = iy + cy, Z = iz + cz;
            const bool valid = ((unsigned)X < GRIDN) & ((unsigned)Y < GRIDN) & ((unsigned)Z < GRIDN);
            const int Xc = min(max(X, 0), GRIDN - 1);
            const int Yc = min(max(Y, 0), GRIDN - 1);
            const int Zc = min(max(Z, 0), GRIDN - 1);
            const unsigned off = (unsigned)((((Xc << 7) + Yc) << 7) + Zc) * 112u;
            const float w = (cx ? rx : 1.f - rx) * (cy ? ry : 1.f - ry) * (cz ? rz : 1.f - rz);
            ow_s[tid][g] = make_uint2(off, __float_as_uint(valid ? w : 0.f));
        }
    }
    __syncthreads();

    // ---- phase 1: coalesced gather, in-register corner reduction ----
    {
        const int s_sub = lane >> 4;          // 0..3
        const int cz    = (lane >> 3) & 1;
        const int q     = lane & 7;
        const int qe    = (q == 7) ? 6 : q;   // dup quad 6, weight forced 0
        const char* base = (const char*)vox_grid;

        for (int it = 0; it < NSAMP / 16; ++it) {   // 12 rounds
            const int s = it * 16 + wave * 4 + s_sub;
            float4 acc = make_float4(0.f, 0.f, 0.f, 0.f);
            #pragma unroll
            for (int pair = 0; pair < 4; ++pair) {
                const uint2 ow = ow_s[s][pair * 2 + cz];
                const float w  = (q == 7) ? 0.f : __uint_as_float(ow.y);
                const float4 v = *(const float4*)(base + ow.x + qe * 16);
                acc.x = fmaf(w, v.x, acc.x);
                acc.y = fmaf(w, v.y, acc.y);
                acc.z = fmaf(w, v.z, acc.z);
                acc.w = fmaf(w, v.w, acc.w);
            }
            acc.x += __shfl_xor(acc.x, 8, 64);
            acc.y += __shfl_xor(acc.y, 8, 64);
            acc.z += __shfl_xor(acc.z, 8, 64);
            acc.w += __shfl_xor(acc.w, 8, 64);
            if (cz == 0 && q < 7) vox_s[s * 7 + q] = acc;
        }
    }
    __syncthreads();

    // ---- phases 2/3: per-sample shading + transmittance scan ----
    float sigma = 0.f, incl = 0.f, cr = 0.f, cg = 0.f, cb = 0.f;
    if (tid < NSAMP) {
        float vox[28];
        #pragma unroll
        for (int q2 = 0; q2 < 7; ++q2) {
            const float4 v = vox_s[tid * 7 + q2];
            vox[q2 * 4 + 0] = v.x; vox[q2 * 4 + 1] = v.y;
            vox[q2 * 4 + 2] = v.z; vox[q2 * 4 + 3] = v.w;
        }

        float sh[9];
        sh[0] = 0.28209479177387814f;
        sh[1] = 0.4886025119029199f * dy;
        sh[2] = 0.4886025119029199f * dz;
        sh[3] = 0.4886025119029199f * dx;
        sh[4] = 1.0925484305920792f * dx * dy;
        sh[5] = 1.0925484305920792f * dy * dz;
        sh[6] = 0.31539156525252005f * (3.f * dz * dz - 1.f);
        sh[7] = 1.0925484305920792f * dx * dz;
        sh[8] = 0.5462742152960396f * (dx * dx - dy * dy);

        sigma = fmaxf(vox[0], 0.f);
        #pragma unroll
        for (int k = 0; k < 9; ++k) {
            cr = fmaf(vox[1 + k],  sh[k], cr);
            cg = fmaf(vox[10 + k], sh[k], cg);
            cb = fmaf(vox[19 + k], sh[k], cb);
        }
        cr = fminf(fmaxf(cr, 0.f), 1.f);
        cg = fminf(fmaxf(cg, 0.f), 1.f);
        cb = fminf(fmaxf(cb, 0.f), 1.f);

        incl = sigma;
        #pragma unroll
        for (int d = 1; d < 64; d <<= 1) {
            const float v = __shfl_up(incl, d, 64);
            if (lane >= d) incl += v;
        }
        if (lane == 63) wtot[wave] = incl;
    }
    __syncthreads();

    if (tid < NSAMP) {
        float off = 0.f;
        for (int wv = 0; wv < wave; ++wv) off += wtot[wv];   // wave-uniform
        const float excl  = off + (incl - sigma);
        const float trans = expf(-excl);
        const float alpha = 1.f - expf(-sigma);
        const float wt    = trans * alpha;

        float r = wt * cr, g2 = wt * cg, b = wt * cb;
        #pragma unroll
        for (int d = 32; d >= 1; d >>= 1) {
            r  += __shfl_xor(r,  d, 64);
            g2 += __shfl_xor(g2, d, 64);
            b  += __shfl_xor(b,  d, 64);
        }
        if (lane == 0) { redr[wave] = r; redg[wave] = g2; redb[wave] = b; }
    }
    __syncthreads();

    if (tid == 0) {
        const float tfinal = expf(-(wtot[0] + wtot[1] + wtot[2]));
        out[ray * 3 + 0] = redr[0] + redr[1] + redr[2] + tfinal;
        out[ray * 3 + 1] = redg[0] + redg[1] + redg[2] + tfinal;
        out[ray * 3 + 2] = redb[0] + redb[1] + redb[2] + tfinal;
    }
    __syncthreads();   // protect ow_s/wtot/red* before next rep overwrites

    } // rep
}

extern "C" void kernel_launch(void* const* d_in, const int* in_sizes, int n_in,
                              void* d_out, int out_size, void* d_ws, size_t ws_size,
                              hipStream_t stream) {
    const float* vox_grid = (const float*)d_in[0];
    const float* origins  = (const float*)d_in[1];
    const float* dirs     = (const float*)d_in[2];
    float*       out      = (float*)d_out;
    hipMemsetAsync(d_ws, 0, 4, stream);   // zero_p[0] = 0.0f (async, capture-safe)
    const int R = in_sizes[1] / 3;        // 2048 rays
    plenoxel_render_kernel<<<R, BLOCK, 0, stream>>>(vox_grid, origins, dirs,
                                                    (const float*)d_ws, out);
}

// Round 6
// 34.776 us; speedup vs baseline: 4.9062x; 4.9062x over previous
//
#include <hip/hip_runtime.h>
#include <math.h>

#define GRIDN 128
#define NSAMP 192
#define BLOCK 256

__global__ __launch_bounds__(BLOCK) void plenoxel_render_kernel(
    const float* __restrict__ vox_grid,   // [128][128][128][28]
    const float* __restrict__ origins,    // [R][3]
    const float* __restrict__ dirs_in,    // [R][3]
    float* __restrict__ out)              // [R][3]
{
    __shared__ uint2  ow_s[NSAMP][8];     // 12288 B {byte offset, weight bits}
    __shared__ float4 scs_s[NSAMP];       //  3072 B {sigma, r, g, b} per sample
    __shared__ float  sh_s[9];
    __shared__ float  wtot[3];
    __shared__ float  redr[3], redg[3], redb[3];

    const int ray  = blockIdx.x;
    const int tid  = threadIdx.x;
    const int lane = tid & 63;
    const int wave = tid >> 6;              // 0..3

    // ---- per-ray setup (uniform per block) ----
    const float ox = origins[ray * 3 + 0];
    const float oy = origins[ray * 3 + 1];
    const float oz = origins[ray * 3 + 2];
    float dx = dirs_in[ray * 3 + 0];
    float dy = dirs_in[ray * 3 + 1];
    float dz = dirs_in[ray * 3 + 2];
    const float rn = 1.0f / sqrtf(dx * dx + dy * dy + dz * dz);
    dx *= rn; dy *= rn; dz *= rn;

    // SH basis into LDS (unit dir: st*cp=dx, st*sp=dy, ct=dz)
    if (tid == 0) {
        sh_s[0] = 0.28209479177387814f;
        sh_s[1] = 0.4886025119029199f * dy;
        sh_s[2] = 0.4886025119029199f * dz;
        sh_s[3] = 0.4886025119029199f * dx;
        sh_s[4] = 1.0925484305920792f * dx * dy;
        sh_s[5] = 1.0925484305920792f * dy * dz;
        sh_s[6] = 0.31539156525252005f * (3.f * dz * dz - 1.f);
        sh_s[7] = 1.0925484305920792f * dx * dz;
        sh_s[8] = 0.5462742152960396f * (dx * dx - dy * dy);
    }

    // ---- phase 0: per-sample corner offsets + weights (thread = sample) ----
    if (tid < NSAMP) {
        const float t  = (float)tid;
        const float px = fmaf(dx, t, ox);
        const float py = fmaf(dy, t, oy);
        const float pz = fmaf(dz, t, oz);
        const float fx = floorf(px), fy = floorf(py), fz = floorf(pz);
        const int   ix = (int)fx, iy = (int)fy, iz = (int)fz;
        const float rx = px - fx, ry = py - fy, rz = pz - fz;
        #pragma unroll
        for (int g = 0; g < 8; ++g) {
            const int cx = (g >> 2) & 1, cy = (g >> 1) & 1, cz = g & 1;
            const int X = ix + cx, Y = iy + cy, Z = iz + cz;
            const bool valid = ((unsigned)X < GRIDN) & ((unsigned)Y < GRIDN) & ((unsigned)Z < GRIDN);
            const int Xc = min(max(X, 0), GRIDN - 1);
            const int Yc = min(max(Y, 0), GRIDN - 1);
            const int Zc = min(max(Z, 0), GRIDN - 1);
            const unsigned off = (unsigned)((((Xc << 7) + Yc) << 7) + Zc) * 112u;
            const float w = (cx ? rx : 1.f - rx) * (cy ? ry : 1.f - ry) * (cz ? rz : 1.f - rz);
            ow_s[tid][g] = make_uint2(off, __float_as_uint(valid ? w : 0.f));
        }
    }
    __syncthreads();

    // ---- per-lane color multipliers (loop-invariant) ----
    // After the cz-fold, lane q holds channels 4q..4q+3.
    const int q = lane & 7;
    float mr[4], mg[4], mb[4];
    #pragma unroll
    for (int j = 0; j < 4; ++j) {
        const int c = q * 4 + j;
        mr[j] = (c >= 1  && c <= 9 ) ? sh_s[c - 1]  : 0.f;
        mg[j] = (c >= 10 && c <= 18) ? sh_s[c - 10] : 0.f;
        mb[j] = (c >= 19 && c <= 27) ? sh_s[c - 19] : 0.f;
    }

    // ---- phase 1: coalesced gather + in-lane shading ----
    // lane = s_sub(2b)*16 + cz(1b)*8 + q(3b); 4 samples per wave-iteration.
    {
        const int s_sub = lane >> 4;          // 0..3
        const int cz    = (lane >> 3) & 1;
        const int qe    = (q == 7) ? 6 : q;   // dup quad 6, weight forced 0
        const char* base = (const char*)vox_grid;

        for (int it = 0; it < NSAMP / 16; ++it) {   // 12 rounds
            const int s = it * 16 + wave * 4 + s_sub;
            float4 acc = make_float4(0.f, 0.f, 0.f, 0.f);
            #pragma unroll
            for (int pair = 0; pair < 4; ++pair) {
                const uint2 ow = ow_s[s][pair * 2 + cz];
                const float w  = (q == 7) ? 0.f : __uint_as_float(ow.y);
                const float4 v = *(const float4*)(base + ow.x + qe * 16);
                acc.x = fmaf(w, v.x, acc.x);
                acc.y = fmaf(w, v.y, acc.y);
                acc.z = fmaf(w, v.z, acc.z);
                acc.w = fmaf(w, v.w, acc.w);
            }
            // fold cz=1 into cz=0 (both halves end with the full corner sum)
            acc.x += __shfl_xor(acc.x, 8, 64);
            acc.y += __shfl_xor(acc.y, 8, 64);
            acc.z += __shfl_xor(acc.z, 8, 64);
            acc.w += __shfl_xor(acc.w, 8, 64);

            // partial colors from this lane's 4 channels
            float pr = acc.x * mr[0] + acc.y * mr[1] + acc.z * mr[2] + acc.w * mr[3];
            float pg = acc.x * mg[0] + acc.y * mg[1] + acc.z * mg[2] + acc.w * mg[3];
            float pb = acc.x * mb[0] + acc.y * mb[1] + acc.z * mb[2] + acc.w * mb[3];
            // sigma: channel 0 lives whole in lane q==0 — no reduce needed
            const float ps = fmaxf(acc.x, 0.f);

            #pragma unroll
            for (int m = 1; m < 8; m <<= 1) {
                pr += __shfl_xor(pr, m, 64);
                pg += __shfl_xor(pg, m, 64);
                pb += __shfl_xor(pb, m, 64);
            }
            if (q == 0 && cz == 0) {
                scs_s[s] = make_float4(ps,
                                       fminf(fmaxf(pr, 0.f), 1.f),
                                       fminf(fmaxf(pg, 0.f), 1.f),
                                       fminf(fmaxf(pb, 0.f), 1.f));
            }
        }
    }
    __syncthreads();

    // ---- phase 2: transmittance scan + accumulation (thread = sample) ----
    float sigma = 0.f, incl = 0.f, cr = 0.f, cg = 0.f, cb = 0.f;
    if (tid < NSAMP) {
        const float4 sc = scs_s[tid];
        sigma = sc.x; cr = sc.y; cg = sc.z; cb = sc.w;

        incl = sigma;
        #pragma unroll
        for (int d = 1; d < 64; d <<= 1) {
            const float v = __shfl_up(incl, d, 64);
            if (lane >= d) incl += v;
        }
        if (lane == 63) wtot[wave] = incl;
    }
    __syncthreads();

    if (tid < NSAMP) {
        float off = 0.f;
        for (int wv = 0; wv < wave; ++wv) off += wtot[wv];   // wave-uniform
        const float excl  = off + (incl - sigma);
        const float trans = expf(-excl);
        const float alpha = 1.f - expf(-sigma);
        const float wt    = trans * alpha;

        float r = wt * cr, g2 = wt * cg, b = wt * cb;
        #pragma unroll
        for (int d = 32; d >= 1; d >>= 1) {
            r  += __shfl_xor(r,  d, 64);
            g2 += __shfl_xor(g2, d, 64);
            b  += __shfl_xor(b,  d, 64);
        }
        if (lane == 0) { redr[wave] = r; redg[wave] = g2; redb[wave] = b; }
    }
    __syncthreads();

    if (tid == 0) {
        const float tfinal = expf(-(wtot[0] + wtot[1] + wtot[2]));
        out[ray * 3 + 0] = redr[0] + redr[1] + redr[2] + tfinal;
        out[ray * 3 + 1] = redg[0] + redg[1] + redg[2] + tfinal;
        out[ray * 3 + 2] = redb[0] + redb[1] + redb[2] + tfinal;
    }
}

extern "C" void kernel_launch(void* const* d_in, const int* in_sizes, int n_in,
                              void* d_out, int out_size, void* d_ws, size_t ws_size,
                              hipStream_t stream) {
    const float* vox_grid = (const float*)d_in[0];
    const float* origins  = (const float*)d_in[1];
    const float* dirs     = (const float*)d_in[2];
    float*       out      = (float*)d_out;
    const int R = in_sizes[1] / 3;   // 2048 rays
    plenoxel_render_kernel<<<R, BLOCK, 0, stream>>>(vox_grid, origins, dirs, out);
}

// Round 7
// 26.459 us; speedup vs baseline: 6.4484x; 1.3143x over previous
//
#include <hip/hip_runtime.h>
#include <math.h>

#define GRIDN 128
#define NSAMP 192
#define BLOCK 256

__global__ __launch_bounds__(BLOCK) void plenoxel_render_kernel(
    const float* __restrict__ vox_grid,   // [128][128][128][28]
    const float* __restrict__ origins,    // [R][3]
    const float* __restrict__ dirs_in,    // [R][3]
    float* __restrict__ out)              // [R][3]
{
    __shared__ uint2  ow_s[NSAMP][8];     // 12288 B {byte offset, weight bits}
    __shared__ float4 scs_s[NSAMP];       //  3072 B {sigma, r, g, b} per sample
    __shared__ float  sh_s[9];
    __shared__ int    lastw[4];           // per-wave highest live sample
    __shared__ float  wtot[3];
    __shared__ float  redr[3], redg[3], redb[3];

    const int ray  = blockIdx.x;
    const int tid  = threadIdx.x;
    const int lane = tid & 63;
    const int wave = tid >> 6;              // 0..3

    // ---- per-ray setup (uniform per block) ----
    const float ox = origins[ray * 3 + 0];
    const float oy = origins[ray * 3 + 1];
    const float oz = origins[ray * 3 + 2];
    float dx = dirs_in[ray * 3 + 0];
    float dy = dirs_in[ray * 3 + 1];
    float dz = dirs_in[ray * 3 + 2];
    const float rn = 1.0f / sqrtf(dx * dx + dy * dy + dz * dz);
    dx *= rn; dy *= rn; dz *= rn;

    // SH basis into LDS (unit dir: st*cp=dx, st*sp=dy, ct=dz)
    if (tid == 0) {
        sh_s[0] = 0.28209479177387814f;
        sh_s[1] = 0.4886025119029199f * dy;
        sh_s[2] = 0.4886025119029199f * dz;
        sh_s[3] = 0.4886025119029199f * dx;
        sh_s[4] = 1.0925484305920792f * dx * dy;
        sh_s[5] = 1.0925484305920792f * dy * dz;
        sh_s[6] = 0.31539156525252005f * (3.f * dz * dz - 1.f);
        sh_s[7] = 1.0925484305920792f * dx * dz;
        sh_s[8] = 0.5462742152960396f * (dx * dx - dy * dy);
    }

    // ---- phase 0: per-sample corner offsets + weights (thread = sample) ----
    bool any_valid = false;
    if (tid < NSAMP) {
        scs_s[tid] = make_float4(0.f, 0.f, 0.f, 0.f);   // dead samples contribute 0
        const float t  = (float)tid;
        const float px = fmaf(dx, t, ox);
        const float py = fmaf(dy, t, oy);
        const float pz = fmaf(dz, t, oz);
        const float fx = floorf(px), fy = floorf(py), fz = floorf(pz);
        const int   ix = (int)fx, iy = (int)fy, iz = (int)fz;
        const float rx = px - fx, ry = py - fy, rz = pz - fz;
        #pragma unroll
        for (int g = 0; g < 8; ++g) {
            const int cx = (g >> 2) & 1, cy = (g >> 1) & 1, cz = g & 1;
            const int X = ix + cx, Y = iy + cy, Z = iz + cz;
            const bool valid = ((unsigned)X < GRIDN) & ((unsigned)Y < GRIDN) & ((unsigned)Z < GRIDN);
            any_valid |= valid;
            const int Xc = min(max(X, 0), GRIDN - 1);
            const int Yc = min(max(Y, 0), GRIDN - 1);
            const int Zc = min(max(Z, 0), GRIDN - 1);
            const unsigned off = (unsigned)((((Xc << 7) + Yc) << 7) + Zc) * 112u;
            const float w = (cx ? rx : 1.f - rx) * (cy ? ry : 1.f - ry) * (cz ? rz : 1.f - rz);
            ow_s[tid][g] = make_uint2(off, __float_as_uint(valid ? w : 0.f));
        }
    }
    // highest live sample index per wave -> block
    {
        const unsigned long long m = __ballot(any_valid);
        if (lane == 0) lastw[wave] = m ? (wave * 64 + 63 - __clzll(m)) : -1;
    }
    __syncthreads();
    const int last_live = max(max(lastw[0], lastw[1]), max(lastw[2], lastw[3]));

    // ---- per-lane color multipliers (loop-invariant) ----
    const int q = lane & 7;
    float mr[4], mg[4], mb[4];
    #pragma unroll
    for (int j = 0; j < 4; ++j) {
        const int c = q * 4 + j;
        mr[j] = (c >= 1  && c <= 9 ) ? sh_s[c - 1]  : 0.f;
        mg[j] = (c >= 10 && c <= 18) ? sh_s[c - 10] : 0.f;
        mb[j] = (c >= 19 && c <= 27) ? sh_s[c - 19] : 0.f;
    }

    // ---- phase 1: coalesced gather + in-lane shading (live prefix only) ----
    // lane = s_sub(2b)*16 + cz(1b)*8 + q(3b); 4 samples per wave-iteration.
    {
        const int s_sub = lane >> 4;          // 0..3
        const int cz    = (lane >> 3) & 1;
        const int qe    = (q == 7) ? 6 : q;   // dup quad 6, weight forced 0
        const char* base = (const char*)vox_grid;

        for (int it = 0; it < NSAMP / 16; ++it) {   // up to 12 rounds
            const int s0 = it * 16 + wave * 4;
            if (s0 > last_live) break;              // wave-uniform: dead suffix
            const int s = s0 + s_sub;
            float4 acc = make_float4(0.f, 0.f, 0.f, 0.f);
            #pragma unroll
            for (int pair = 0; pair < 4; ++pair) {
                const uint2 ow = ow_s[s][pair * 2 + cz];
                const float w  = (q == 7) ? 0.f : __uint_as_float(ow.y);
                const float4 v = *(const float4*)(base + ow.x + qe * 16);
                acc.x = fmaf(w, v.x, acc.x);
                acc.y = fmaf(w, v.y, acc.y);
                acc.z = fmaf(w, v.z, acc.z);
                acc.w = fmaf(w, v.w, acc.w);
            }
            // fold cz=1 into cz=0
            acc.x += __shfl_xor(acc.x, 8, 64);
            acc.y += __shfl_xor(acc.y, 8, 64);
            acc.z += __shfl_xor(acc.z, 8, 64);
            acc.w += __shfl_xor(acc.w, 8, 64);

            float pr = acc.x * mr[0] + acc.y * mr[1] + acc.z * mr[2] + acc.w * mr[3];
            float pg = acc.x * mg[0] + acc.y * mg[1] + acc.z * mg[2] + acc.w * mg[3];
            float pb = acc.x * mb[0] + acc.y * mb[1] + acc.z * mb[2] + acc.w * mb[3];
            const float ps = fmaxf(acc.x, 0.f);     // channel 0 whole in lane q==0

            #pragma unroll
            for (int m = 1; m < 8; m <<= 1) {
                pr += __shfl_xor(pr, m, 64);
                pg += __shfl_xor(pg, m, 64);
                pb += __shfl_xor(pb, m, 64);
            }
            if (q == 0 && cz == 0) {
                scs_s[s] = make_float4(ps,
                                       fminf(fmaxf(pr, 0.f), 1.f),
                                       fminf(fmaxf(pg, 0.f), 1.f),
                                       fminf(fmaxf(pb, 0.f), 1.f));
            }
        }
    }
    __syncthreads();

    // ---- phase 2: transmittance scan + accumulation (thread = sample) ----
    float sigma = 0.f, incl = 0.f, cr = 0.f, cg = 0.f, cb = 0.f;
    if (tid < NSAMP) {
        const float4 sc = scs_s[tid];
        sigma = sc.x; cr = sc.y; cg = sc.z; cb = sc.w;

        incl = sigma;
        #pragma unroll
        for (int d = 1; d < 64; d <<= 1) {
            const float v = __shfl_up(incl, d, 64);
            if (lane >= d) incl += v;
        }
        if (lane == 63) wtot[wave] = incl;
    }
    __syncthreads();

    if (tid < NSAMP) {
        float off = 0.f;
        for (int wv = 0; wv < wave; ++wv) off += wtot[wv];   // wave-uniform
        const float excl  = off + (incl - sigma);
        const float trans = expf(-excl);
        const float alpha = 1.f - expf(-sigma);
        const float wt    = trans * alpha;

        float r = wt * cr, g2 = wt * cg, b = wt * cb;
        #pragma unroll
        for (int d = 32; d >= 1; d >>= 1) {
            r  += __shfl_xor(r,  d, 64);
            g2 += __shfl_xor(g2, d, 64);
            b  += __shfl_xor(b,  d, 64);
        }
        if (lane == 0) { redr[wave] = r; redg[wave] = g2; redb[wave] = b; }
    }
    __syncthreads();

    if (tid == 0) {
        const float tfinal = expf(-(wtot[0] + wtot[1] + wtot[2]));
        out[ray * 3 + 0] = redr[0] + redr[1] + redr[2] + tfinal;
        out[ray * 3 + 1] = redg[0] + redg[1] + redg[2] + tfinal;
        out[ray * 3 + 2] = redb[0] + redb[1] + redb[2] + tfinal;
    }
}

extern "C" void kernel_launch(void* const* d_in, const int* in_sizes, int n_in,
                              void* d_out, int out_size, void* d_ws, size_t ws_size,
                              hipStream_t stream) {
    const float* vox_grid = (const float*)d_in[0];
    const float* origins  = (const float*)d_in[1];
    const float* dirs     = (const float*)d_in[2];
    float*       out      = (float*)d_out;
    const int R = in_sizes[1] / 3;   // 2048 rays
    plenoxel_render_kernel<<<R, BLOCK, 0, stream>>>(vox_grid, origins, dirs, out);
}

// Round 8
// 24.264 us; speedup vs baseline: 7.0317x; 1.0905x over previous
//
#include <hip/hip_runtime.h>
#include <math.h>

#define GRIDN 128
#define NSAMP 192
#define BLOCK 256

__global__ __launch_bounds__(BLOCK) void plenoxel_render_kernel(
    const float* __restrict__ vox_grid,   // [128][128][128][28]
    const float* __restrict__ origins,    // [R][3]
    const float* __restrict__ dirs_in,    // [R][3]
    float* __restrict__ out)              // [R][3]
{
    __shared__ uint2  ow_s[NSAMP][9];     // 13824 B; stride 9 (72B) = bank spread
    __shared__ float4 scs_s[NSAMP];       //  3072 B {sigma, r, g, b}
    __shared__ float  sh_s[9];
    __shared__ int    lastw[4];
    __shared__ float  wtot[3];
    __shared__ float  redr[3], redg[3], redb[3];

    const int ray  = blockIdx.x;
    const int tid  = threadIdx.x;
    const int lane = tid & 63;
    const int wave = tid >> 6;              // 0..3

    // ---- per-ray setup (uniform per block) ----
    const float ox = origins[ray * 3 + 0];
    const float oy = origins[ray * 3 + 1];
    const float oz = origins[ray * 3 + 2];
    float dx = dirs_in[ray * 3 + 0];
    float dy = dirs_in[ray * 3 + 1];
    float dz = dirs_in[ray * 3 + 2];
    const float rn = 1.0f / sqrtf(dx * dx + dy * dy + dz * dz);
    dx *= rn; dy *= rn; dz *= rn;

    // SH basis into LDS (unit dir: st*cp=dx, st*sp=dy, ct=dz)
    if (tid == 0) {
        sh_s[0] = 0.28209479177387814f;
        sh_s[1] = 0.4886025119029199f * dy;
        sh_s[2] = 0.4886025119029199f * dz;
        sh_s[3] = 0.4886025119029199f * dx;
        sh_s[4] = 1.0925484305920792f * dx * dy;
        sh_s[5] = 1.0925484305920792f * dy * dz;
        sh_s[6] = 0.31539156525252005f * (3.f * dz * dz - 1.f);
        sh_s[7] = 1.0925484305920792f * dx * dz;
        sh_s[8] = 0.5462742152960396f * (dx * dx - dy * dy);
    }

    // ---- phase 0: per-sample corner offsets + weights (thread = sample) ----
    bool any_valid = false;
    if (tid < NSAMP) {
        scs_s[tid] = make_float4(0.f, 0.f, 0.f, 0.f);   // dead samples contribute 0
        const float t  = (float)tid;
        const float px = fmaf(dx, t, ox);
        const float py = fmaf(dy, t, oy);
        const float pz = fmaf(dz, t, oz);
        const float fx = floorf(px), fy = floorf(py), fz = floorf(pz);
        const int   ix = (int)fx, iy = (int)fy, iz = (int)fz;
        const float rx = px - fx, ry = py - fy, rz = pz - fz;
        #pragma unroll
        for (int g = 0; g < 8; ++g) {
            const int cx = (g >> 2) & 1, cy = (g >> 1) & 1, cz = g & 1;
            const int X = ix + cx, Y = iy + cy, Z = iz + cz;
            const bool valid = ((unsigned)X < GRIDN) & ((unsigned)Y < GRIDN) & ((unsigned)Z < GRIDN);
            any_valid |= valid;
            const int Xc = min(max(X, 0), GRIDN - 1);
            const int Yc = min(max(Y, 0), GRIDN - 1);
            const int Zc = min(max(Z, 0), GRIDN - 1);
            const unsigned off = (unsigned)((((Xc << 7) + Yc) << 7) + Zc) * 112u;
            const float w = (cx ? rx : 1.f - rx) * (cy ? ry : 1.f - ry) * (cz ? rz : 1.f - rz);
            ow_s[tid][g] = make_uint2(off, __float_as_uint(valid ? w : 0.f));
        }
    }
    {
        const unsigned long long m = __ballot(any_valid);
        if (lane == 0) lastw[wave] = m ? (wave * 64 + 63 - __clzll(m)) : -1;
    }
    __syncthreads();
    const int last_live = max(max(lastw[0], lastw[1]), max(lastw[2], lastw[3]));

    // ---- per-lane color multipliers (loop-invariant) ----
    const int q = lane & 7;
    float mr[4], mg[4], mb[4];
    #pragma unroll
    for (int j = 0; j < 4; ++j) {
        const int c = q * 4 + j;
        mr[j] = (c >= 1  && c <= 9 ) ? sh_s[c - 1]  : 0.f;
        mg[j] = (c >= 10 && c <= 18) ? sh_s[c - 10] : 0.f;
        mb[j] = (c >= 19 && c <= 27) ? sh_s[c - 19] : 0.f;
    }

    // ---- phase 1: gather, all-8-corners-in-lane (live prefix only) ----
    // lane = s_sub(3b)*8 + q(3b); 8 samples per wave-iteration.
    // 8 independent global loads in flight per lane; zero fold shuffles;
    // sigma needs no cross-lane (lane q==0 holds channel 0 whole).
    {
        const int s_sub = lane >> 3;          // 0..7
        const int qe    = (q == 7) ? 6 : q;   // dup quad 6, weight forced 0
        const char* base = (const char*)vox_grid;

        for (int it = 0; it < NSAMP / 32; ++it) {   // up to 6 rounds
            const int sbase = it * 32 + wave * 8;
            if (sbase > last_live) break;           // wave-uniform dead suffix
            const int s = sbase + s_sub;
            float4 acc = make_float4(0.f, 0.f, 0.f, 0.f);
            #pragma unroll
            for (int g = 0; g < 8; ++g) {
                const uint2 ow = ow_s[s][g];
                const float w  = (q == 7) ? 0.f : __uint_as_float(ow.y);
                const float4 v = *(const float4*)(base + ow.x + qe * 16);
                acc.x = fmaf(w, v.x, acc.x);
                acc.y = fmaf(w, v.y, acc.y);
                acc.z = fmaf(w, v.z, acc.z);
                acc.w = fmaf(w, v.w, acc.w);
            }

            float pr = acc.x * mr[0] + acc.y * mr[1] + acc.z * mr[2] + acc.w * mr[3];
            float pg = acc.x * mg[0] + acc.y * mg[1] + acc.z * mg[2] + acc.w * mg[3];
            float pb = acc.x * mb[0] + acc.y * mb[1] + acc.z * mb[2] + acc.w * mb[3];
            const float ps = fmaxf(acc.x, 0.f);     // full sigma in lane q==0

            #pragma unroll
            for (int m = 1; m < 8; m <<= 1) {
                pr += __shfl_xor(pr, m, 64);
                pg += __shfl_xor(pg, m, 64);
                pb += __shfl_xor(pb, m, 64);
            }
            if (q == 0) {
                scs_s[s] = make_float4(ps,
                                       fminf(fmaxf(pr, 0.f), 1.f),
                                       fminf(fmaxf(pg, 0.f), 1.f),
                                       fminf(fmaxf(pb, 0.f), 1.f));
            }
        }
    }
    __syncthreads();

    // ---- phase 2: transmittance scan + accumulation (thread = sample) ----
    float sigma = 0.f, incl = 0.f, cr = 0.f, cg = 0.f, cb = 0.f;
    if (tid < NSAMP) {
        const float4 sc = scs_s[tid];
        sigma = sc.x; cr = sc.y; cg = sc.z; cb = sc.w;

        incl = sigma;
        #pragma unroll
        for (int d = 1; d < 64; d <<= 1) {
            const float v = __shfl_up(incl, d, 64);
            if (lane >= d) incl += v;
        }
        if (lane == 63) wtot[wave] = incl;
    }
    __syncthreads();

    if (tid < NSAMP) {
        float off = 0.f;
        for (int wv = 0; wv < wave; ++wv) off += wtot[wv];   // wave-uniform
        const float excl  = off + (incl - sigma);
        const float trans = expf(-excl);
        const float alpha = 1.f - expf(-sigma);
        const float wt    = trans * alpha;

        float r = wt * cr, g2 = wt * cg, b = wt * cb;
        #pragma unroll
        for (int d = 32; d >= 1; d >>= 1) {
            r  += __shfl_xor(r,  d, 64);
            g2 += __shfl_xor(g2, d, 64);
            b  += __shfl_xor(b,  d, 64);
        }
        if (lane == 0) { redr[wave] = r; redg[wave] = g2; redb[wave] = b; }
    }
    __syncthreads();

    if (tid == 0) {
        const float tfinal = expf(-(wtot[0] + wtot[1] + wtot[2]));
        out[ray * 3 + 0] = redr[0] + redr[1] + redr[2] + tfinal;
        out[ray * 3 + 1] = redg[0] + redg[1] + redg[2] + tfinal;
        out[ray * 3 + 2] = redb[0] + redb[1] + redb[2] + tfinal;
    }
}

extern "C" void kernel_launch(void* const* d_in, const int* in_sizes, int n_in,
                              void* d_out, int out_size, void* d_ws, size_t ws_size,
                              hipStream_t stream) {
    const float* vox_grid = (const float*)d_in[0];
    const float* origins  = (const float*)d_in[1];
    const float* dirs     = (const float*)d_in[2];
    float*       out      = (float*)d_out;
    const int R = in_sizes[1] / 3;   // 2048 rays
    plenoxel_render_kernel<<<R, BLOCK, 0, stream>>>(vox_grid, origins, dirs, out);
}